// Round 11
// baseline (804.638 us; speedup 1.0000x reference)
//
#include <hip/hip_runtime.h>
#include <math.h>

#define NN 50000
#define NPAD 50048           // 782 * 64
#define NE 800000
#define D 128
#define DE 16
#define NL 3
#define LN_EPS 1e-5f
#define NB_SCAN 49           // ceil(50000/1024)
#define MAXP (NE + 15 * NN)  // padded-CSR upper bound

typedef __attribute__((ext_vector_type(8))) short short8;
typedef __attribute__((ext_vector_type(8))) unsigned short ushort8;
typedef __attribute__((ext_vector_type(4))) float floatx4;
typedef __attribute__((ext_vector_type(4))) unsigned int uintx4;
typedef __attribute__((ext_vector_type(2))) int intx2;

__device__ __forceinline__ unsigned short f2bf(float f) {
  unsigned u = __float_as_uint(f);
  u = (u + 0x7fffu + ((u >> 16) & 1u)) >> 16;
  return (unsigned short)u;
}
__device__ __forceinline__ float bfl(unsigned v) { return __uint_as_float(v << 16); }
__device__ __forceinline__ float bfh(unsigned v) { return __uint_as_float(v & 0xffff0000u); }

// ---------------- preprocessing ----------------

__global__ void k_hist(const int* __restrict__ col, int* __restrict__ cnt) {
  int e = blockIdx.x * blockDim.x + threadIdx.x;
  if (e < NE) atomicAdd(&cnt[col[e]], 1);
}

__device__ __forceinline__ int pdeg(int d) { return (d + 15) & ~15; }

__global__ __launch_bounds__(1024) void k_chunk_sum(const int* __restrict__ cnt,
                                                    int* __restrict__ chunk_sum) {
  int i = blockIdx.x * 1024 + threadIdx.x;
  int v = (i < NN) ? pdeg(cnt[i]) : 0;
  #pragma unroll
  for (int off = 32; off; off >>= 1) v += __shfl_down(v, off);
  __shared__ int ws_[16];
  int lane = threadIdx.x & 63, w = threadIdx.x >> 6;
  if (lane == 0) ws_[w] = v;
  __syncthreads();
  if (threadIdx.x < 16) {
    int s = ws_[threadIdx.x];
    #pragma unroll
    for (int off = 8; off; off >>= 1) s += __shfl_down(s, off);
    if (threadIdx.x == 0) chunk_sum[blockIdx.x] = s;
  }
}

__global__ __launch_bounds__(64) void k_chunk_scan(const int* __restrict__ chunk_sum,
                                                   int* __restrict__ chunk_off,
                                                   int* __restrict__ col_ptr) {
  int t = threadIdx.x;
  int v = (t < NB_SCAN) ? chunk_sum[t] : 0;
  int incl = v;
  #pragma unroll
  for (int off = 1; off < 64; off <<= 1) {
    int u = __shfl_up(incl, off);
    if (t >= off) incl += u;
  }
  if (t < NB_SCAN) chunk_off[t] = incl - v;
  if (t == 63) col_ptr[NN] = incl;   // total padded length
}

// scan + emit col_ptr/cursor/dis + zero the pad slots (csr w=0, attr rows 0)
__global__ __launch_bounds__(1024) void k_scan_apply(const int* __restrict__ cnt,
                                                     const int* __restrict__ chunk_off,
                                                     int* __restrict__ col_ptr,
                                                     int* __restrict__ cursor,
                                                     float* __restrict__ dis,
                                                     int2* __restrict__ csr_rw,
                                                     unsigned short* __restrict__ attr_bf) {
  __shared__ int buf[1024];
  int t = threadIdx.x;
  int i = blockIdx.x * 1024 + t;
  int d = (i < NN) ? cnt[i] : 0;
  int v = pdeg(d);
  buf[t] = v;
  __syncthreads();
  int acc = v;
  for (int off = 1; off < 1024; off <<= 1) {
    int add = (t >= off) ? buf[t - off] : 0;
    __syncthreads();
    acc += add;
    buf[t] = acc;
    __syncthreads();
  }
  if (i < NN) {
    int cp = chunk_off[blockIdx.x] + acc - v;
    col_ptr[i] = cp;
    cursor[i] = cp;
    dis[i] = (d > 0) ? rsqrtf((float)d) : 0.0f;
    int npad = v - d;
    ushort8 z = {0, 0, 0, 0, 0, 0, 0, 0};
    for (int j = 0; j < npad; ++j) {
      int p = cp + d + j;
      csr_rw[p] = make_int2(0, 0);
      ushort8* dst = (ushort8*)(attr_bf + ((size_t)p << 4));
      dst[0] = z;
      dst[1] = z;
    }
  }
}

// scatter CSR entry + converted attr (sequential reads, scattered 40 B writes)
__global__ void k_fill(const int* __restrict__ row, const int* __restrict__ col,
                       const float* __restrict__ dis, int* __restrict__ cursor,
                       const float* __restrict__ edge_attr,
                       int2* __restrict__ csr_rw, unsigned short* __restrict__ attr_bf) {
  int e = blockIdx.x * blockDim.x + threadIdx.x;
  if (e >= NE) return;
  int c = col[e], r = row[e];
  float w = dis[r] * dis[c];
  int p = atomicAdd(&cursor[c], 1);
  csr_rw[p] = make_int2(r, __float_as_int(w));
  const float4* src = (const float4*)(edge_attr + ((size_t)e << 4));
  float4 f0 = src[0], f1 = src[1], f2 = src[2], f3 = src[3];
  ushort8 o0, o1;
  o0[0] = f2bf(f0.x); o0[1] = f2bf(f0.y); o0[2] = f2bf(f0.z); o0[3] = f2bf(f0.w);
  o0[4] = f2bf(f1.x); o0[5] = f2bf(f1.y); o0[6] = f2bf(f1.z); o0[7] = f2bf(f1.w);
  o1[0] = f2bf(f2.x); o1[1] = f2bf(f2.y); o1[2] = f2bf(f2.z); o1[3] = f2bf(f2.w);
  o1[4] = f2bf(f3.x); o1[5] = f2bf(f3.y); o1[6] = f2bf(f3.z); o1[7] = f2bf(f3.w);
  ushort8* dst = (ushort8*)(attr_bf + ((size_t)p << 4));
  dst[0] = o0;
  dst[1] = o1;
}

// merged prep: weight transpose (wt), W1^T fragments (w1t), x -> bf16 (h)
#define PREP_R1 (NL * 2 * D * D)
#define PREP_R2 (PREP_R1 + NL * D * 32)
#define PREP_R3 (PREP_R2 + NN * D / 4)
__global__ void k_prep(const float* __restrict__ lin_w, const float* __restrict__ edge_w2,
                       const float* __restrict__ edge_w1, const float* __restrict__ edge_b1,
                       const float* __restrict__ x,
                       unsigned short* __restrict__ wt, unsigned short* __restrict__ w1t,
                       unsigned short* __restrict__ h) {
  int idx = blockIdx.x * blockDim.x + threadIdx.x;
  if (idx < PREP_R1) {
    int ls = idx / (D * D);
    int rem = idx - ls * (D * D);
    int n = rem >> 7, k = rem & 127;
    int l = ls >> 1, s = ls & 1;
    const float* W = (s == 0) ? (lin_w + (size_t)l * D * D) : (edge_w2 + (size_t)l * D * D);
    wt[idx] = f2bf(W[k * D + n]);
  } else if (idx < PREP_R2) {
    int j = idx - PREP_R1;
    int l = j / (D * 32);
    int rem = j - l * (D * 32);
    int nf = rem >> 5, k = rem & 31;
    float v = 0.f;
    if (k < DE) v = edge_w1[(size_t)l * DE * D + k * D + nf];
    else if (k == DE) v = edge_b1[(size_t)l * D + nf];
    w1t[j] = f2bf(v);
  } else if (idx < PREP_R3) {
    int i = idx - PREP_R2;
    float4 v = ((const float4*)x)[i];
    ushort4 o;
    o.x = f2bf(v.x); o.y = f2bf(v.y); o.z = f2bf(v.z); o.w = f2bf(v.w);
    ((ushort4*)h)[i] = o;
  }
}

// ---------------- per-layer aggregation: 4 nodes/wave, dual-chunk iterations ----------------
// Abuf[n][0:128]   = sum_e w_e * h[row_e]             (unmasked gathers; pads have w=0)
// Abuf[n][128:256] = sum_e relu(attr_e @ W1_l + b1_l) (MFMA per 16-edge chunk)
// Nodes with >=2 remaining chunks process two chunks per iteration: both chunks'
// csr/h/attr loads issue before either consumes -> half the dependent round-trips.

__global__ __launch_bounds__(256, 4) void k_agg(
    const unsigned short* __restrict__ hIn, const unsigned short* __restrict__ attr_bf,
    const unsigned short* __restrict__ w1tL,
    const int* __restrict__ col_ptr, const int* __restrict__ cnt,
    const int2* __restrict__ csr_rw, unsigned short* __restrict__ Abuf) {
  int t = threadIdx.x;
  int lane = t & 63;
  int sub = lane >> 4, fl = lane & 15;
  int nBase = (blockIdx.x * 4 + (t >> 6)) * 4;   // wave handles nodes nBase..nBase+3

  short8 bfr[8];
  #pragma unroll
  for (int tt = 0; tt < 8; ++tt)
    bfr[tt] = *(const short8*)(const void*)(w1tL + (tt * 16 + fl) * 32 + sub * 8);

  floatx4 zeroc = {0.f, 0.f, 0.f, 0.f};
  int pcur = col_ptr[nBase];

  #pragma unroll
  for (int i = 0; i < 4; ++i) {
    int n = nBase + i;
    int pend = col_ptr[n + 1];
    int dend = pcur + cnt[n];

    float aH[8], sE[8];
    #pragma unroll
    for (int k = 0; k < 8; ++k) { aH[k] = 0.f; sE[k] = 0.f; }

    int base = pcur;
    // ---- dual-chunk iterations ----
    for (; base + 32 <= pend; base += 32) {
      intx2 qA[4], qB[4];
      #pragma unroll
      for (int jj = 0; jj < 4; ++jj) {
        qA[jj] = __builtin_nontemporal_load((const intx2*)(const void*)&csr_rw[base + jj * 4 + sub]);
        qB[jj] = __builtin_nontemporal_load((const intx2*)(const void*)&csr_rw[base + 16 + jj * 4 + sub]);
      }
      uint4 hvA[4], hvB[4];
      #pragma unroll
      for (int jj = 0; jj < 4; ++jj) {
        hvA[jj] = *(const uint4*)(hIn + (((size_t)qA[jj][0]) << 7) + (fl << 3));
        hvB[jj] = *(const uint4*)(hIn + (((size_t)qB[jj][0]) << 7) + (fl << 3));
      }
      short8 aA = {0, 0, 0, 0, 0, 0, 0, 0};
      short8 aB = {0, 0, 0, 0, 0, 0, 0, 0};
      if (sub < 2) {
        uintx4 r0 = __builtin_nontemporal_load(
            (const uintx4*)(const void*)(attr_bf + (((size_t)(base + fl)) << 4) + sub * 8));
        uintx4 r1 = __builtin_nontemporal_load(
            (const uintx4*)(const void*)(attr_bf + (((size_t)(base + 16 + fl)) << 4) + sub * 8));
        aA = *(short8*)&r0;
        aB = *(short8*)&r1;
      } else if (sub == 2) {
        aA[0] = (base + fl < dend) ? (short)0x3F80 : (short)0;
        aB[0] = (base + 16 + fl < dend) ? (short)0x3F80 : (short)0;
      }
      #pragma unroll
      for (int tt = 0; tt < 8; ++tt) {
        floatx4 dA = __builtin_amdgcn_mfma_f32_16x16x32_bf16(aA, bfr[tt], zeroc, 0, 0, 0);
        floatx4 dB = __builtin_amdgcn_mfma_f32_16x16x32_bf16(aB, bfr[tt], zeroc, 0, 0, 0);
        sE[tt] += fmaxf(dA[0], 0.f) + fmaxf(dA[1], 0.f) + fmaxf(dA[2], 0.f) + fmaxf(dA[3], 0.f)
                + fmaxf(dB[0], 0.f) + fmaxf(dB[1], 0.f) + fmaxf(dB[2], 0.f) + fmaxf(dB[3], 0.f);
      }
      #pragma unroll
      for (int jj = 0; jj < 4; ++jj) {
        float wA = __int_as_float(qA[jj][1]);
        float wB = __int_as_float(qB[jj][1]);
        aH[0] = fmaf(wA, bfl(hvA[jj].x), aH[0]); aH[1] = fmaf(wA, bfh(hvA[jj].x), aH[1]);
        aH[2] = fmaf(wA, bfl(hvA[jj].y), aH[2]); aH[3] = fmaf(wA, bfh(hvA[jj].y), aH[3]);
        aH[4] = fmaf(wA, bfl(hvA[jj].z), aH[4]); aH[5] = fmaf(wA, bfh(hvA[jj].z), aH[5]);
        aH[6] = fmaf(wA, bfl(hvA[jj].w), aH[6]); aH[7] = fmaf(wA, bfh(hvA[jj].w), aH[7]);
        aH[0] = fmaf(wB, bfl(hvB[jj].x), aH[0]); aH[1] = fmaf(wB, bfh(hvB[jj].x), aH[1]);
        aH[2] = fmaf(wB, bfl(hvB[jj].y), aH[2]); aH[3] = fmaf(wB, bfh(hvB[jj].y), aH[3]);
        aH[4] = fmaf(wB, bfl(hvB[jj].z), aH[4]); aH[5] = fmaf(wB, bfh(hvB[jj].z), aH[5]);
        aH[6] = fmaf(wB, bfl(hvB[jj].w), aH[6]); aH[7] = fmaf(wB, bfh(hvB[jj].w), aH[7]);
      }
    }
    // ---- single-chunk tail ----
    for (; base < pend; base += 16) {
      intx2 q[4];
      #pragma unroll
      for (int jj = 0; jj < 4; ++jj)
        q[jj] = __builtin_nontemporal_load((const intx2*)(const void*)&csr_rw[base + jj * 4 + sub]);
      uint4 hv[4];
      #pragma unroll
      for (int jj = 0; jj < 4; ++jj)
        hv[jj] = *(const uint4*)(hIn + (((size_t)q[jj][0]) << 7) + (fl << 3));
      short8 a = {0, 0, 0, 0, 0, 0, 0, 0};
      if (sub < 2) {
        uintx4 araw = __builtin_nontemporal_load(
            (const uintx4*)(const void*)(attr_bf + (((size_t)(base + fl)) << 4) + sub * 8));
        a = *(short8*)&araw;
      } else if (sub == 2) {
        a[0] = (base + fl < dend) ? (short)0x3F80 : (short)0;
      }
      #pragma unroll
      for (int tt = 0; tt < 8; ++tt) {
        floatx4 dacc = __builtin_amdgcn_mfma_f32_16x16x32_bf16(a, bfr[tt], zeroc, 0, 0, 0);
        sE[tt] += fmaxf(dacc[0], 0.f) + fmaxf(dacc[1], 0.f) +
                  fmaxf(dacc[2], 0.f) + fmaxf(dacc[3], 0.f);
      }
      #pragma unroll
      for (int jj = 0; jj < 4; ++jj) {
        float wi = __int_as_float(q[jj][1]);
        aH[0] = fmaf(wi, bfl(hv[jj].x), aH[0]); aH[1] = fmaf(wi, bfh(hv[jj].x), aH[1]);
        aH[2] = fmaf(wi, bfl(hv[jj].y), aH[2]); aH[3] = fmaf(wi, bfh(hv[jj].y), aH[3]);
        aH[4] = fmaf(wi, bfl(hv[jj].z), aH[4]); aH[5] = fmaf(wi, bfh(hv[jj].z), aH[5]);
        aH[6] = fmaf(wi, bfl(hv[jj].w), aH[6]); aH[7] = fmaf(wi, bfh(hv[jj].w), aH[7]);
      }
    }

    // ---- once-per-node cross-sub reduction + store ----
    #pragma unroll
    for (int k = 0; k < 8; ++k) {
      aH[k] += __shfl_xor(aH[k], 16);
      aH[k] += __shfl_xor(aH[k], 32);
      sE[k] += __shfl_xor(sE[k], 16);
      sE[k] += __shfl_xor(sE[k], 32);
    }
    unsigned short* rowp = Abuf + (size_t)n * 256;
    if (sub == 0) {
      uint4 o;
      o.x = (unsigned)f2bf(aH[0]) | ((unsigned)f2bf(aH[1]) << 16);
      o.y = (unsigned)f2bf(aH[2]) | ((unsigned)f2bf(aH[3]) << 16);
      o.z = (unsigned)f2bf(aH[4]) | ((unsigned)f2bf(aH[5]) << 16);
      o.w = (unsigned)f2bf(aH[6]) | ((unsigned)f2bf(aH[7]) << 16);
      *(uint4*)(rowp + (fl << 3)) = o;
    }
    #pragma unroll
    for (int tt = 0; tt < 8; ++tt)
      if ((tt >> 1) == sub) rowp[128 + tt * 16 + fl] = f2bf(sE[tt]);

    pcur = pend;
  }
}

// ---------------- fused MFMA GEMM (K=256) + bias/deg + LayerNorm + relu ----------------

template <bool LAST>
__global__ __launch_bounds__(256, 4) void k_fused(
    const unsigned short* __restrict__ Abuf,   // [NPAD][256] bf16
    const unsigned short* __restrict__ wtL,    // [2][128][128] bf16 (this layer)
    const int* __restrict__ cnt,
    const float* __restrict__ b2, const float* __restrict__ bias,
    const float* __restrict__ lnw, const float* __restrict__ lnb,
    unsigned short* __restrict__ hOut, float* __restrict__ fOut) {
  __shared__ unsigned short bt[128 * 128];   // XOR-swizzled 16B chunks
  int t = threadIdx.x;
  int w = t >> 6, lane = t & 63;
  int quad = lane >> 4, ln = lane & 15;
  int rowBase = blockIdx.x * 64 + w * 16;

  floatx4 acc[8];
  floatx4 zero = {0.f, 0.f, 0.f, 0.f};
  #pragma unroll
  for (int i = 0; i < 8; ++i) acc[i] = zero;

  float b2n[8], biasn[8], lnwn[8], lnbn[8];
  #pragma unroll
  for (int i = 0; i < 8; ++i) {
    int nc = i * 16 + ln;
    b2n[i] = b2[nc]; biasn[i] = bias[nc]; lnwn[i] = lnw[nc]; lnbn[i] = lnb[nc];
  }

  const unsigned short* Arow = Abuf + (size_t)(rowBase + ln) * 256;

  #pragma unroll
  for (int p = 0; p < 2; ++p) {
    if (p) __syncthreads();
    const unsigned short* src = wtL + p * (D * D);
    #pragma unroll
    for (int j = 0; j < 8; ++j) {
      int E = t * 8 + j * 2048;                  // element index: n*128 + k
      int nn_ = E >> 7, kblk = (E & 127) >> 3;
      int dst = nn_ * 128 + ((kblk ^ (nn_ & 15)) << 3);
      *(ushort8*)&bt[dst] = *(const ushort8*)&src[E];
    }
    __syncthreads();
    #pragma unroll
    for (int k0 = 0; k0 < 128; k0 += 32) {
      short8 a = *(const short8*)(const void*)(Arow + p * 128 + k0 + quad * 8);
      int cblk = (k0 >> 3) + quad;
      #pragma unroll
      for (int tt = 0; tt < 8; ++tt) {
        int src_off = (tt * 16 + ln) * 128 + ((cblk ^ ln) << 3);
        short8 b = *(const short8*)(const void*)&bt[src_off];
        acc[tt] = __builtin_amdgcn_mfma_f32_16x16x32_bf16(a, b, acc[tt], 0, 0, 0);
      }
    }
  }

  // epilogue: D[m=quad*4+r][n=tt*16+ln]
  float degf[4];
  #pragma unroll
  for (int r = 0; r < 4; ++r) {
    int m = rowBase + quad * 4 + r;
    degf[r] = (m < NN) ? (float)cnt[m] : 0.f;
  }
  float v[8][4];
  float s[4] = {0, 0, 0, 0}, sq[4] = {0, 0, 0, 0};
  #pragma unroll
  for (int tt = 0; tt < 8; ++tt) {
    #pragma unroll
    for (int r = 0; r < 4; ++r) {
      float x = acc[tt][r] + degf[r] * b2n[tt] + biasn[tt];
      v[tt][r] = x;
      s[r] += x;
      sq[r] += x * x;
    }
  }
  #pragma unroll
  for (int r = 0; r < 4; ++r) {
    #pragma unroll
    for (int m_ = 8; m_ >= 1; m_ >>= 1) {
      s[r] += __shfl_xor(s[r], m_);
      sq[r] += __shfl_xor(sq[r], m_);
    }
  }
  #pragma unroll
  for (int r = 0; r < 4; ++r) {
    int m = rowBase + quad * 4 + r;
    float mu = s[r] * (1.f / D);
    float var = sq[r] * (1.f / D) - mu * mu;
    float rs = rsqrtf(var + LN_EPS);
    if (m < NN) {
      #pragma unroll
      for (int tt = 0; tt < 8; ++tt) {
        float y = fmaxf((v[tt][r] - mu) * rs * lnwn[tt] + lnbn[tt], 0.f);
        int nc = tt * 16 + ln;
        if (LAST) fOut[(size_t)m * D + nc] = y;
        else      hOut[(size_t)m * D + nc] = f2bf(y);
      }
    }
  }
}

// ---------------- launch ----------------

static inline size_t align256(size_t x) { return (x + 255) & ~(size_t)255; }

extern "C" void kernel_launch(void* const* d_in, const int* in_sizes, int n_in,
                              void* d_out, int out_size, void* d_ws, size_t ws_size,
                              hipStream_t stream) {
  const float* x         = (const float*)d_in[0];
  const float* edge_attr = (const float*)d_in[1];
  const float* lin_w     = (const float*)d_in[2];
  const float* edge_w1   = (const float*)d_in[3];
  const float* edge_b1   = (const float*)d_in[4];
  const float* edge_w2   = (const float*)d_in[5];
  const float* edge_b2   = (const float*)d_in[6];
  const float* bias      = (const float*)d_in[7];
  const float* ln_w      = (const float*)d_in[8];
  const float* ln_b      = (const float*)d_in[9];
  const int*   edge_idx  = (const int*)d_in[10];
  const int* row = edge_idx;
  const int* col = edge_idx + NE;
  float* out = (float*)d_out;

  char* wsp = (char*)d_ws;
  size_t off = 0;
  int* cnt       = (int*)(wsp + off); off = align256(off + sizeof(int) * NN);
  int* cursor    = (int*)(wsp + off); off = align256(off + sizeof(int) * NN);
  int* col_ptr   = (int*)(wsp + off); off = align256(off + sizeof(int) * (NN + 1));
  float* dis     = (float*)(wsp + off); off = align256(off + sizeof(float) * NN);
  int* chunk_sum = (int*)(wsp + off); off = align256(off + sizeof(int) * 64);
  int* chunk_off = (int*)(wsp + off); off = align256(off + sizeof(int) * 64);
  int2* csr_rw   = (int2*)(wsp + off); off = align256(off + sizeof(int2) * (size_t)MAXP);
  unsigned short* attr_bf = (unsigned short*)(wsp + off); off = align256(off + sizeof(short) * (size_t)MAXP * DE);
  unsigned short* wt  = (unsigned short*)(wsp + off); off = align256(off + sizeof(short) * NL * 2 * D * D);
  unsigned short* w1t = (unsigned short*)(wsp + off); off = align256(off + sizeof(short) * NL * D * 32);
  unsigned short* hA = (unsigned short*)(wsp + off); off = align256(off + sizeof(short) * (size_t)NPAD * D);
  unsigned short* hB = (unsigned short*)(wsp + off); off = align256(off + sizeof(short) * (size_t)NPAD * D);
  unsigned short* Abuf = (unsigned short*)(wsp + off); off = align256(off + sizeof(short) * (size_t)NPAD * 256);

  hipMemsetAsync(cnt, 0, sizeof(int) * NN, stream);

  k_hist<<<(NE + 255) / 256, 256, 0, stream>>>(col, cnt);
  k_chunk_sum<<<NB_SCAN, 1024, 0, stream>>>(cnt, chunk_sum);
  k_chunk_scan<<<1, 64, 0, stream>>>(chunk_sum, chunk_off, col_ptr);
  k_scan_apply<<<NB_SCAN, 1024, 0, stream>>>(cnt, chunk_off, col_ptr, cursor, dis,
                                             csr_rw, attr_bf);
  k_fill<<<(NE + 255) / 256, 256, 0, stream>>>(row, col, dis, cursor, edge_attr, csr_rw, attr_bf);
  k_prep<<<(PREP_R3 + 255) / 256, 256, 0, stream>>>(lin_w, edge_w2, edge_w1, edge_b1, x,
                                                    wt, w1t, hA);

  const int fused_blocks = NPAD / 64;
  const int agg_blocks = (NN + 15) / 16;   // 4 waves/block, 4 nodes/wave
  unsigned short* hcur = hA;
  unsigned short* hnxt = hB;
  for (int l = 0; l < NL; ++l) {
    k_agg<<<agg_blocks, 256, 0, stream>>>(
        hcur, attr_bf, w1t + (size_t)l * D * 32, col_ptr, cnt, csr_rw, Abuf);
    const unsigned short* wtL = wt + (size_t)l * 2 * D * D;
    const float* b2L = edge_b2 + (size_t)l * D;
    const float* biasL = bias + (size_t)l * D;
    const float* lnwL = ln_w + (size_t)l * D;
    const float* lnbL = ln_b + (size_t)l * D;
    if (l == NL - 1) {
      k_fused<true><<<fused_blocks, 256, 0, stream>>>(Abuf, wtL, cnt, b2L, biasL, lnwL, lnbL,
                                                      (unsigned short*)nullptr, out);
    } else {
      k_fused<false><<<fused_blocks, 256, 0, stream>>>(Abuf, wtL, cnt, b2L, biasL, lnwL, lnbL,
                                                       hnxt, (float*)nullptr);
    }
    unsigned short* tmp = hcur; hcur = hnxt; hnxt = tmp;
  }
}

// Round 12
// 461.026 us; speedup vs baseline: 1.7453x; 1.7453x over previous
//
#include <hip/hip_runtime.h>
#include <math.h>

#define NN 50000
#define NPAD 50048           // 782 * 64
#define NE 800000
#define D 128
#define DE 16
#define NL 3
#define LN_EPS 1e-5f
#define NB_SCAN 49           // ceil(50000/1024)
#define MAXP (NE + 15 * NN)  // padded-CSR upper bound

typedef __attribute__((ext_vector_type(8))) short short8;
typedef __attribute__((ext_vector_type(8))) unsigned short ushort8;
typedef __attribute__((ext_vector_type(4))) float floatx4;
typedef __attribute__((ext_vector_type(4))) unsigned int uintx4;
typedef __attribute__((ext_vector_type(2))) int intx2;

__device__ __forceinline__ unsigned short f2bf(float f) {
  unsigned u = __float_as_uint(f);
  u = (u + 0x7fffu + ((u >> 16) & 1u)) >> 16;
  return (unsigned short)u;
}
__device__ __forceinline__ float bfl(unsigned v) { return __uint_as_float(v << 16); }
__device__ __forceinline__ float bfh(unsigned v) { return __uint_as_float(v & 0xffff0000u); }

// ---------------- preprocessing ----------------

__global__ void k_hist(const int* __restrict__ col, int* __restrict__ cnt) {
  int e = blockIdx.x * blockDim.x + threadIdx.x;
  if (e < NE) atomicAdd(&cnt[col[e]], 1);
}

__device__ __forceinline__ int pdeg(int d) { return (d + 15) & ~15; }

__global__ __launch_bounds__(1024) void k_chunk_sum(const int* __restrict__ cnt,
                                                    int* __restrict__ chunk_sum) {
  int i = blockIdx.x * 1024 + threadIdx.x;
  int v = (i < NN) ? pdeg(cnt[i]) : 0;
  #pragma unroll
  for (int off = 32; off; off >>= 1) v += __shfl_down(v, off);
  __shared__ int ws_[16];
  int lane = threadIdx.x & 63, w = threadIdx.x >> 6;
  if (lane == 0) ws_[w] = v;
  __syncthreads();
  if (threadIdx.x < 16) {
    int s = ws_[threadIdx.x];
    #pragma unroll
    for (int off = 8; off; off >>= 1) s += __shfl_down(s, off);
    if (threadIdx.x == 0) chunk_sum[blockIdx.x] = s;
  }
}

__global__ __launch_bounds__(64) void k_chunk_scan(const int* __restrict__ chunk_sum,
                                                   int* __restrict__ chunk_off,
                                                   int* __restrict__ col_ptr) {
  int t = threadIdx.x;
  int v = (t < NB_SCAN) ? chunk_sum[t] : 0;
  int incl = v;
  #pragma unroll
  for (int off = 1; off < 64; off <<= 1) {
    int u = __shfl_up(incl, off);
    if (t >= off) incl += u;
  }
  if (t < NB_SCAN) chunk_off[t] = incl - v;
  if (t == 63) col_ptr[NN] = incl;   // total padded length
}

// scan + emit col_ptr/cursor/dis + zero the pad slots (csr w=0, attr rows 0)
__global__ __launch_bounds__(1024) void k_scan_apply(const int* __restrict__ cnt,
                                                     const int* __restrict__ chunk_off,
                                                     int* __restrict__ col_ptr,
                                                     int* __restrict__ cursor,
                                                     float* __restrict__ dis,
                                                     int2* __restrict__ csr_rw,
                                                     unsigned short* __restrict__ attr_bf) {
  __shared__ int buf[1024];
  int t = threadIdx.x;
  int i = blockIdx.x * 1024 + t;
  int d = (i < NN) ? cnt[i] : 0;
  int v = pdeg(d);
  buf[t] = v;
  __syncthreads();
  int acc = v;
  for (int off = 1; off < 1024; off <<= 1) {
    int add = (t >= off) ? buf[t - off] : 0;
    __syncthreads();
    acc += add;
    buf[t] = acc;
    __syncthreads();
  }
  if (i < NN) {
    int cp = chunk_off[blockIdx.x] + acc - v;
    col_ptr[i] = cp;
    cursor[i] = cp;
    dis[i] = (d > 0) ? rsqrtf((float)d) : 0.0f;
    int npad = v - d;
    ushort8 z = {0, 0, 0, 0, 0, 0, 0, 0};
    for (int j = 0; j < npad; ++j) {
      int p = cp + d + j;
      csr_rw[p] = make_int2(0, 0);
      ushort8* dst = (ushort8*)(attr_bf + ((size_t)p << 4));
      dst[0] = z;
      dst[1] = z;
    }
  }
}

// scatter CSR entry + converted attr (sequential reads, scattered 40 B writes)
__global__ void k_fill(const int* __restrict__ row, const int* __restrict__ col,
                       const float* __restrict__ dis, int* __restrict__ cursor,
                       const float* __restrict__ edge_attr,
                       int2* __restrict__ csr_rw, unsigned short* __restrict__ attr_bf) {
  int e = blockIdx.x * blockDim.x + threadIdx.x;
  if (e >= NE) return;
  int c = col[e], r = row[e];
  float w = dis[r] * dis[c];
  int p = atomicAdd(&cursor[c], 1);
  csr_rw[p] = make_int2(r, __float_as_int(w));
  const float4* src = (const float4*)(edge_attr + ((size_t)e << 4));
  float4 f0 = src[0], f1 = src[1], f2 = src[2], f3 = src[3];
  ushort8 o0, o1;
  o0[0] = f2bf(f0.x); o0[1] = f2bf(f0.y); o0[2] = f2bf(f0.z); o0[3] = f2bf(f0.w);
  o0[4] = f2bf(f1.x); o0[5] = f2bf(f1.y); o0[6] = f2bf(f1.z); o0[7] = f2bf(f1.w);
  o1[0] = f2bf(f2.x); o1[1] = f2bf(f2.y); o1[2] = f2bf(f2.z); o1[3] = f2bf(f2.w);
  o1[4] = f2bf(f3.x); o1[5] = f2bf(f3.y); o1[6] = f2bf(f3.z); o1[7] = f2bf(f3.w);
  ushort8* dst = (ushort8*)(attr_bf + ((size_t)p << 4));
  dst[0] = o0;
  dst[1] = o1;
}

// merged prep: weight transpose (wt), W1^T fragments (w1t), x -> bf16 (h)
#define PREP_R1 (NL * 2 * D * D)
#define PREP_R2 (PREP_R1 + NL * D * 32)
#define PREP_R3 (PREP_R2 + NN * D / 4)
__global__ void k_prep(const float* __restrict__ lin_w, const float* __restrict__ edge_w2,
                       const float* __restrict__ edge_w1, const float* __restrict__ edge_b1,
                       const float* __restrict__ x,
                       unsigned short* __restrict__ wt, unsigned short* __restrict__ w1t,
                       unsigned short* __restrict__ h) {
  int idx = blockIdx.x * blockDim.x + threadIdx.x;
  if (idx < PREP_R1) {
    int ls = idx / (D * D);
    int rem = idx - ls * (D * D);
    int n = rem >> 7, k = rem & 127;
    int l = ls >> 1, s = ls & 1;
    const float* W = (s == 0) ? (lin_w + (size_t)l * D * D) : (edge_w2 + (size_t)l * D * D);
    wt[idx] = f2bf(W[k * D + n]);
  } else if (idx < PREP_R2) {
    int j = idx - PREP_R1;
    int l = j / (D * 32);
    int rem = j - l * (D * 32);
    int nf = rem >> 5, k = rem & 31;
    float v = 0.f;
    if (k < DE) v = edge_w1[(size_t)l * DE * D + k * D + nf];
    else if (k == DE) v = edge_b1[(size_t)l * D + nf];
    w1t[j] = f2bf(v);
  } else if (idx < PREP_R3) {
    int i = idx - PREP_R2;
    float4 v = ((const float4*)x)[i];
    ushort4 o;
    o.x = f2bf(v.x); o.y = f2bf(v.y); o.z = f2bf(v.z); o.w = f2bf(v.w);
    ((ushort4*)h)[i] = o;
  }
}

// ---------------- per-layer aggregation: 2 sequential nodes per wave ----------------
// Abuf[n][0:128]   = sum_e w_e * h[row_e]             (unmasked gathers; pads have w=0)
// Abuf[n][128:256] = sum_e relu(attr_e @ W1_l + b1_l) (MFMA per 16-edge chunk)
// 2 nodes/wave (vs 4 in R9): 6250 blocks -> ~3 full residency rounds, small tail.

__global__ __launch_bounds__(256, 4) void k_agg(
    const unsigned short* __restrict__ hIn, const unsigned short* __restrict__ attr_bf,
    const unsigned short* __restrict__ w1tL,
    const int* __restrict__ col_ptr, const int* __restrict__ cnt,
    const int2* __restrict__ csr_rw, unsigned short* __restrict__ Abuf) {
  int t = threadIdx.x;
  int lane = t & 63;
  int sub = lane >> 4, fl = lane & 15;
  int nBase = (blockIdx.x * 4 + (t >> 6)) * 2;   // wave handles nodes nBase..nBase+1
  if (nBase >= NN) return;

  // B fragments once per wave (shared by both nodes)
  short8 bfr[8];
  #pragma unroll
  for (int tt = 0; tt < 8; ++tt)
    bfr[tt] = *(const short8*)(const void*)(w1tL + (tt * 16 + fl) * 32 + sub * 8);

  floatx4 zeroc = {0.f, 0.f, 0.f, 0.f};
  int pcur = col_ptr[nBase];

  #pragma unroll
  for (int i = 0; i < 2; ++i) {
    int n = nBase + i;
    if (n >= NN) break;
    int pend = col_ptr[n + 1];     // sequential; end of node i = start of node i+1
    int dend = pcur + cnt[n];      // real-edge end (for constant-1 masking)

    float aH[8], sE[8];
    #pragma unroll
    for (int k = 0; k < 8; ++k) { aH[k] = 0.f; sE[k] = 0.f; }

    for (int base = pcur; base < pend; base += 16) {
      // ---- h gather: lane (sub, fl) = edge slot sub of each 4-edge group, features fl*8.. ----
      #pragma unroll
      for (int jj = 0; jj < 4; ++jj) {
        int idx = base + jj * 4 + sub;
        intx2 q = __builtin_nontemporal_load((const intx2*)(const void*)&csr_rw[idx]);
        float wi = __int_as_float(q[1]);
        uint4 hv = *(const uint4*)(hIn + (((size_t)q[0]) << 7) + (fl << 3));
        aH[0] = fmaf(wi, bfl(hv.x), aH[0]);
        aH[1] = fmaf(wi, bfh(hv.x), aH[1]);
        aH[2] = fmaf(wi, bfl(hv.y), aH[2]);
        aH[3] = fmaf(wi, bfh(hv.y), aH[3]);
        aH[4] = fmaf(wi, bfl(hv.z), aH[4]);
        aH[5] = fmaf(wi, bfh(hv.z), aH[5]);
        aH[6] = fmaf(wi, bfl(hv.w), aH[6]);
        aH[7] = fmaf(wi, bfh(hv.w), aH[7]);
      }
      // ---- edge MLP: A[m=fl][k=sub*8+j] ----
      int idx2 = base + fl;
      short8 a = {0, 0, 0, 0, 0, 0, 0, 0};
      if (sub < 2) {
        uintx4 araw = __builtin_nontemporal_load(
            (const uintx4*)(const void*)(attr_bf + (((size_t)idx2) << 4) + sub * 8));
        a = *(short8*)&araw;                      // pads are zero
      } else if (sub == 2) {
        a[0] = (idx2 < dend) ? (short)0x3F80 : (short)0;  // const-1 slot folds b1, masks pads
      }
      #pragma unroll
      for (int tt = 0; tt < 8; ++tt) {
        floatx4 dacc = __builtin_amdgcn_mfma_f32_16x16x32_bf16(a, bfr[tt], zeroc, 0, 0, 0);
        sE[tt] += fmaxf(dacc[0], 0.f) + fmaxf(dacc[1], 0.f) +
                  fmaxf(dacc[2], 0.f) + fmaxf(dacc[3], 0.f);
      }
    }

    // ---- once-per-node cross-sub reduction + store ----
    #pragma unroll
    for (int k = 0; k < 8; ++k) {
      aH[k] += __shfl_xor(aH[k], 16);
      aH[k] += __shfl_xor(aH[k], 32);
      sE[k] += __shfl_xor(sE[k], 16);
      sE[k] += __shfl_xor(sE[k], 32);
    }
    unsigned short* rowp = Abuf + (size_t)n * 256;
    if (sub == 0) {
      uint4 o;
      o.x = (unsigned)f2bf(aH[0]) | ((unsigned)f2bf(aH[1]) << 16);
      o.y = (unsigned)f2bf(aH[2]) | ((unsigned)f2bf(aH[3]) << 16);
      o.z = (unsigned)f2bf(aH[4]) | ((unsigned)f2bf(aH[5]) << 16);
      o.w = (unsigned)f2bf(aH[6]) | ((unsigned)f2bf(aH[7]) << 16);
      *(uint4*)(rowp + (fl << 3)) = o;
    }
    #pragma unroll
    for (int tt = 0; tt < 8; ++tt)
      if ((tt >> 1) == sub) rowp[128 + tt * 16 + fl] = f2bf(sE[tt]);

    pcur = pend;
  }
}

// ---------------- fused MFMA GEMM (K=256) + bias/deg + LayerNorm + relu ----------------

template <bool LAST>
__global__ __launch_bounds__(256, 4) void k_fused(
    const unsigned short* __restrict__ Abuf,   // [NPAD][256] bf16
    const unsigned short* __restrict__ wtL,    // [2][128][128] bf16 (this layer)
    const int* __restrict__ cnt,
    const float* __restrict__ b2, const float* __restrict__ bias,
    const float* __restrict__ lnw, const float* __restrict__ lnb,
    unsigned short* __restrict__ hOut, float* __restrict__ fOut) {
  __shared__ unsigned short bt[128 * 128];   // XOR-swizzled 16B chunks
  int t = threadIdx.x;
  int w = t >> 6, lane = t & 63;
  int quad = lane >> 4, ln = lane & 15;
  int rowBase = blockIdx.x * 64 + w * 16;

  floatx4 acc[8];
  floatx4 zero = {0.f, 0.f, 0.f, 0.f};
  #pragma unroll
  for (int i = 0; i < 8; ++i) acc[i] = zero;

  float b2n[8], biasn[8], lnwn[8], lnbn[8];
  #pragma unroll
  for (int i = 0; i < 8; ++i) {
    int nc = i * 16 + ln;
    b2n[i] = b2[nc]; biasn[i] = bias[nc]; lnwn[i] = lnw[nc]; lnbn[i] = lnb[nc];
  }

  const unsigned short* Arow = Abuf + (size_t)(rowBase + ln) * 256;

  #pragma unroll
  for (int p = 0; p < 2; ++p) {
    if (p) __syncthreads();
    const unsigned short* src = wtL + p * (D * D);
    #pragma unroll
    for (int j = 0; j < 8; ++j) {
      int E = t * 8 + j * 2048;                  // element index: n*128 + k
      int nn_ = E >> 7, kblk = (E & 127) >> 3;
      int dst = nn_ * 128 + ((kblk ^ (nn_ & 15)) << 3);
      *(ushort8*)&bt[dst] = *(const ushort8*)&src[E];
    }
    __syncthreads();
    #pragma unroll
    for (int k0 = 0; k0 < 128; k0 += 32) {
      short8 a = *(const short8*)(const void*)(Arow + p * 128 + k0 + quad * 8);
      int cblk = (k0 >> 3) + quad;
      #pragma unroll
      for (int tt = 0; tt < 8; ++tt) {
        int src_off = (tt * 16 + ln) * 128 + ((cblk ^ ln) << 3);
        short8 b = *(const short8*)(const void*)&bt[src_off];
        acc[tt] = __builtin_amdgcn_mfma_f32_16x16x32_bf16(a, b, acc[tt], 0, 0, 0);
      }
    }
  }

  // epilogue: D[m=quad*4+r][n=tt*16+ln]
  float degf[4];
  #pragma unroll
  for (int r = 0; r < 4; ++r) {
    int m = rowBase + quad * 4 + r;
    degf[r] = (m < NN) ? (float)cnt[m] : 0.f;
  }
  float v[8][4];
  float s[4] = {0, 0, 0, 0}, sq[4] = {0, 0, 0, 0};
  #pragma unroll
  for (int tt = 0; tt < 8; ++tt) {
    #pragma unroll
    for (int r = 0; r < 4; ++r) {
      float x = acc[tt][r] + degf[r] * b2n[tt] + biasn[tt];
      v[tt][r] = x;
      s[r] += x;
      sq[r] += x * x;
    }
  }
  #pragma unroll
  for (int r = 0; r < 4; ++r) {
    #pragma unroll
    for (int m_ = 8; m_ >= 1; m_ >>= 1) {
      s[r] += __shfl_xor(s[r], m_);
      sq[r] += __shfl_xor(sq[r], m_);
    }
  }
  #pragma unroll
  for (int r = 0; r < 4; ++r) {
    int m = rowBase + quad * 4 + r;
    float mu = s[r] * (1.f / D);
    float var = sq[r] * (1.f / D) - mu * mu;
    float rs = rsqrtf(var + LN_EPS);
    if (m < NN) {
      #pragma unroll
      for (int tt = 0; tt < 8; ++tt) {
        float y = fmaxf((v[tt][r] - mu) * rs * lnwn[tt] + lnbn[tt], 0.f);
        int nc = tt * 16 + ln;
        if (LAST) fOut[(size_t)m * D + nc] = y;
        else      hOut[(size_t)m * D + nc] = f2bf(y);
      }
    }
  }
}

// ---------------- launch ----------------

static inline size_t align256(size_t x) { return (x + 255) & ~(size_t)255; }

extern "C" void kernel_launch(void* const* d_in, const int* in_sizes, int n_in,
                              void* d_out, int out_size, void* d_ws, size_t ws_size,
                              hipStream_t stream) {
  const float* x         = (const float*)d_in[0];
  const float* edge_attr = (const float*)d_in[1];
  const float* lin_w     = (const float*)d_in[2];
  const float* edge_w1   = (const float*)d_in[3];
  const float* edge_b1   = (const float*)d_in[4];
  const float* edge_w2   = (const float*)d_in[5];
  const float* edge_b2   = (const float*)d_in[6];
  const float* bias      = (const float*)d_in[7];
  const float* ln_w      = (const float*)d_in[8];
  const float* ln_b      = (const float*)d_in[9];
  const int*   edge_idx  = (const int*)d_in[10];
  const int* row = edge_idx;
  const int* col = edge_idx + NE;
  float* out = (float*)d_out;

  char* wsp = (char*)d_ws;
  size_t off = 0;
  int* cnt       = (int*)(wsp + off); off = align256(off + sizeof(int) * NN);
  int* cursor    = (int*)(wsp + off); off = align256(off + sizeof(int) * NN);
  int* col_ptr   = (int*)(wsp + off); off = align256(off + sizeof(int) * (NN + 1));
  float* dis     = (float*)(wsp + off); off = align256(off + sizeof(float) * NN);
  int* chunk_sum = (int*)(wsp + off); off = align256(off + sizeof(int) * 64);
  int* chunk_off = (int*)(wsp + off); off = align256(off + sizeof(int) * 64);
  int2* csr_rw   = (int2*)(wsp + off); off = align256(off + sizeof(int2) * (size_t)MAXP);
  unsigned short* attr_bf = (unsigned short*)(wsp + off); off = align256(off + sizeof(short) * (size_t)MAXP * DE);
  unsigned short* wt  = (unsigned short*)(wsp + off); off = align256(off + sizeof(short) * NL * 2 * D * D);
  unsigned short* w1t = (unsigned short*)(wsp + off); off = align256(off + sizeof(short) * NL * D * 32);
  unsigned short* hA = (unsigned short*)(wsp + off); off = align256(off + sizeof(short) * (size_t)NPAD * D);
  unsigned short* hB = (unsigned short*)(wsp + off); off = align256(off + sizeof(short) * (size_t)NPAD * D);
  unsigned short* Abuf = (unsigned short*)(wsp + off); off = align256(off + sizeof(short) * (size_t)NPAD * 256);

  hipMemsetAsync(cnt, 0, sizeof(int) * NN, stream);

  k_hist<<<(NE + 255) / 256, 256, 0, stream>>>(col, cnt);
  k_chunk_sum<<<NB_SCAN, 1024, 0, stream>>>(cnt, chunk_sum);
  k_chunk_scan<<<1, 64, 0, stream>>>(chunk_sum, chunk_off, col_ptr);
  k_scan_apply<<<NB_SCAN, 1024, 0, stream>>>(cnt, chunk_off, col_ptr, cursor, dis,
                                             csr_rw, attr_bf);
  k_fill<<<(NE + 255) / 256, 256, 0, stream>>>(row, col, dis, cursor, edge_attr, csr_rw, attr_bf);
  k_prep<<<(PREP_R3 + 255) / 256, 256, 0, stream>>>(lin_w, edge_w2, edge_w1, edge_b1, x,
                                                    wt, w1t, hA);

  const int fused_blocks = NPAD / 64;
  const int agg_blocks = (NN + 7) / 8;   // 4 waves/block, 2 nodes/wave
  unsigned short* hcur = hA;
  unsigned short* hnxt = hB;
  for (int l = 0; l < NL; ++l) {
    k_agg<<<agg_blocks, 256, 0, stream>>>(
        hcur, attr_bf, w1t + (size_t)l * D * 32, col_ptr, cnt, csr_rw, Abuf);
    const unsigned short* wtL = wt + (size_t)l * 2 * D * D;
    const float* b2L = edge_b2 + (size_t)l * D;
    const float* biasL = bias + (size_t)l * D;
    const float* lnwL = ln_w + (size_t)l * D;
    const float* lnbL = ln_b + (size_t)l * D;
    if (l == NL - 1) {
      k_fused<true><<<fused_blocks, 256, 0, stream>>>(Abuf, wtL, cnt, b2L, biasL, lnwL, lnbL,
                                                      (unsigned short*)nullptr, out);
    } else {
      k_fused<false><<<fused_blocks, 256, 0, stream>>>(Abuf, wtL, cnt, b2L, biasL, lnwL, lnbL,
                                                       hnxt, (float*)nullptr);
    }
    unsigned short* tmp = hcur; hcur = hnxt; hnxt = tmp;
  }
}